// Round 2
// baseline (8211.327 us; speedup 1.0000x reference)
//
#include <hip/hip_runtime.h>
#include <hip/hip_bf16.h>

#define CC 64
#define HH 512
#define WWI 512
#define HWX (HH*WWI)
#define CHWX (CC*HWX)
#define EPSV 1e-5f

using bf16 = __hip_bfloat16;

__device__ __forceinline__ float b2f(bf16 v){ return __bfloat162float(v); }
__device__ __forceinline__ bf16 f2b(float v){ return __float2bfloat16(v); }

// 256-thread block, 4 waves of 64. Reduce (v1,v2) and atomicAdd into s1,s2.
__device__ __forceinline__ void block_reduce_atomic(float v1, float v2,
                                                    float* s1, float* s2){
  #pragma unroll
  for (int o = 32; o > 0; o >>= 1){
    v1 += __shfl_down(v1, o);
    v2 += __shfl_down(v2, o);
  }
  __shared__ float a1[4], a2[4];
  int lane = threadIdx.x & 63, wid = threadIdx.x >> 6;
  if (lane == 0){ a1[wid] = v1; a2[wid] = v2; }
  __syncthreads();
  if (threadIdx.x == 0){
    atomicAdd(s1, a1[0]+a1[1]+a1[2]+a1[3]);
    atomicAdd(s2, a2[0]+a2[1]+a2[2]+a2[3]);
  }
}

// -------- separable 1-D pooling (max or min), fp32 --------
template<bool ISMAX, bool ROW, int P>
__global__ void pool1d(const float* __restrict__ in, float* __restrict__ out){
  int idx = blockIdx.x * 256 + threadIdx.x;       // over CHWX (exact multiple)
  int xw = idx & (WWI - 1);
  int y  = (idx >> 9) & (HH - 1);
  float m = ISMAX ? -3.4e38f : 3.4e38f;
  if (ROW){
    int lo = max(xw - P, 0), hi = min(xw + P, WWI - 1);
    int base = idx - xw;
    for (int j = lo; j <= hi; ++j){
      float v = in[base + j];
      m = ISMAX ? fmaxf(m, v) : fminf(m, v);
    }
  } else {
    int lo = max(y - P, 0), hi = min(y + P, HH - 1);
    int base = idx - y * WWI;
    for (int j = lo; j <= hi; ++j){
      float v = in[base + j * WWI];
      m = ISMAX ? fmaxf(m, v) : fminf(m, v);
    }
  }
  out[idx] = m;
}

// -------- depthwise KxK conv (zero pad) + per-channel stats --------
template<int K>
__global__ void dwconv_stats(const float* __restrict__ in,
                             const float* __restrict__ wgt,
                             const float* __restrict__ bias,
                             float* __restrict__ outF,
                             float* __restrict__ s1, float* __restrict__ s2){
  const int P = K / 2;
  int c = blockIdx.z;
  int pix = blockIdx.x * 256 + threadIdx.x;       // HWX exact multiple of 256
  int y = pix >> 9, xw = pix & (WWI - 1);
  const float* ip = in + (size_t)c * HWX;
  const float* wp = wgt + c * K * K;
  float acc = bias[c];
  #pragma unroll
  for (int dy = -P; dy <= P; ++dy){
    int yy = y + dy;
    if ((unsigned)yy >= HH) continue;
    #pragma unroll
    for (int dx = -P; dx <= P; ++dx){
      int xx = xw + dx;
      if ((unsigned)xx >= WWI) continue;
      acc += wp[(dy + P) * K + (dx + P)] * ip[yy * WWI + xx];
    }
  }
  outF[(size_t)c * HWX + pix] = acc;
  block_reduce_atomic(acc, acc * acc, s1 + c, s2 + c);
}

// -------- mu/rsqrt finalize --------
__global__ void finalize_stats(const float* __restrict__ s1,
                               const float* __restrict__ s2,
                               float* __restrict__ mu, float* __restrict__ rs,
                               int n, float invN){
  int i = blockIdx.x * 256 + threadIdx.x;
  if (i >= n) return;
  float m = s1[i] * invN;
  float v = fmaxf(s2[i] * invN - m * m, 0.f);
  mu[i] = m;
  rs[i] = rsqrtf(v + EPSV);
}

// -------- d = sgn*(relu(norm(F)) - x), in-place, + stats --------
__global__ void diff_stats(float* __restrict__ F, const float* __restrict__ x,
                           const float* __restrict__ mu, const float* __restrict__ rs,
                           float sgn, float* __restrict__ s1, float* __restrict__ s2){
  int c = blockIdx.z;
  size_t i = (size_t)c * HWX + blockIdx.x * 256 + threadIdx.x;
  float t = fmaxf((F[i] - mu[c]) * rs[c], 0.f);
  float d = sgn * (t - x[i]);
  F[i] = d;
  block_reduce_atomic(d, d * d, s1 + c, s2 + c);
}

// -------- 3x3 depthwise conv of normalized d, accumulate into comb --------
// conv3(norm(d)) = rs*(conv3_nobias(d) - mu*sum_valid(w)) + b
__global__ void conv3_acc(const float* __restrict__ F,
                          const float* __restrict__ mu, const float* __restrict__ rs,
                          const float* __restrict__ w3, const float* __restrict__ b3,
                          float* __restrict__ comb, int first){
  int c = blockIdx.z;
  int pix = blockIdx.x * 256 + threadIdx.x;
  int y = pix >> 9, xw = pix & (WWI - 1);
  float wreg[9];
  #pragma unroll
  for (int j = 0; j < 9; ++j) wreg[j] = w3[c * 9 + j];
  const float* ip = F + (size_t)c * HWX;
  float acc = 0.f, wsum = 0.f;
  #pragma unroll
  for (int dy = -1; dy <= 1; ++dy){
    int yy = y + dy;
    if ((unsigned)yy >= HH) continue;
    #pragma unroll
    for (int dx = -1; dx <= 1; ++dx){
      int xx = xw + dx;
      if ((unsigned)xx >= WWI) continue;
      float wv = wreg[(dy + 1) * 3 + dx + 1];
      acc += wv * ip[yy * WWI + xx];
      wsum += wv;
    }
  }
  float o = rs[c] * (acc - mu[c] * wsum) + b3[c];
  size_t oi = (size_t)c * HWX + pix;
  comb[oi] = first ? o : (comb[oi] + o);
}

// -------- Conv3d #1: (1,1,C,H,W) -> (3,C,H,W), zero pad, bf16 store + stats --------
__global__ void conv3d1(const float* __restrict__ comb,
                        const float* __restrict__ wt, const float* __restrict__ bt,
                        bf16* __restrict__ T,
                        float* __restrict__ s1, float* __restrict__ s2){
  int oc = blockIdx.y, d = blockIdx.z;
  int pix = blockIdx.x * 256 + threadIdx.x;
  int y = pix >> 9, xw = pix & (WWI - 1);
  float wv[27];
  #pragma unroll
  for (int j = 0; j < 27; ++j) wv[j] = wt[oc * 27 + j];
  float acc = bt[oc];
  #pragma unroll
  for (int dd = 0; dd < 3; ++dd){
    int dz = d + dd - 1;
    if ((unsigned)dz >= CC) continue;
    const float* ip = comb + (size_t)dz * HWX;
    #pragma unroll
    for (int dh = 0; dh < 3; ++dh){
      int yy = y + dh - 1;
      if ((unsigned)yy >= HH) continue;
      #pragma unroll
      for (int dw = 0; dw < 3; ++dw){
        int xx = xw + dw - 1;
        if ((unsigned)xx >= WWI) continue;
        acc += wv[dd * 9 + dh * 3 + dw] * ip[yy * WWI + xx];
      }
    }
  }
  bf16 hv = f2b(acc);
  float av = b2f(hv);                 // stats consistent with stored bf16
  int ch = oc * CC + d;
  T[(size_t)ch * HWX + pix] = hv;
  block_reduce_atomic(av, av * av, s1 + ch, s2 + ch);
}

// -------- Conv3d #2 on relu(norm(T)) + sigmoid-gate epilogue --------
__global__ void conv3d2_final(const bf16* __restrict__ T,
                              const float* __restrict__ mu, const float* __restrict__ rs,
                              const float* __restrict__ wt2, const float* __restrict__ bt2,
                              const float* __restrict__ x, float* __restrict__ out){
  int d = blockIdx.z;
  int pix = blockIdx.x * 256 + threadIdx.x;
  int y = pix >> 9, xw = pix & (WWI - 1);
  float acc = bt2[0];
  #pragma unroll
  for (int i3 = 0; i3 < 3; ++i3){
    #pragma unroll
    for (int dd = 0; dd < 3; ++dd){
      int dz = d + dd - 1;
      if ((unsigned)dz >= CC) continue;
      int ch = i3 * CC + dz;
      float m = mu[ch], r = rs[ch];
      const bf16* tp = T + (size_t)ch * HWX;
      #pragma unroll
      for (int dh = 0; dh < 3; ++dh){
        int yy = y + dh - 1;
        if ((unsigned)yy >= HH) continue;
        #pragma unroll
        for (int dw = 0; dw < 3; ++dw){
          int xx = xw + dw - 1;
          if ((unsigned)xx >= WWI) continue;
          float tv = b2f(tp[yy * WWI + xx]);
          acc += wt2[(i3 * 3 + dd) * 9 + dh * 3 + dw] * fmaxf((tv - m) * r, 0.f);
        }
      }
    }
  }
  float sg = 1.f / (1.f + __expf(-acc));
  float xv = x[(size_t)d * HWX + pix];
  out[(size_t)d * HWX + pix] = fmaxf(xv * sg, 0.f);
}

extern "C" void kernel_launch(void* const* d_in, const int* in_sizes, int n_in,
                              void* d_out, int out_size, void* d_ws, size_t ws_size,
                              hipStream_t stream){
  const float* x     = (const float*)d_in[0];
  const float* w_wt5 = (const float*)d_in[1];
  const float* b_wt5 = (const float*)d_in[2];
  const float* w_wt9 = (const float*)d_in[3];
  const float* b_wt9 = (const float*)d_in[4];
  const float* w_bt5 = (const float*)d_in[5];
  const float* b_bt5 = (const float*)d_in[6];
  const float* w_bt9 = (const float*)d_in[7];
  const float* b_bt9 = (const float*)d_in[8];
  const float* w_wn  = (const float*)d_in[9];
  const float* b_wn  = (const float*)d_in[10];
  const float* w_t1  = (const float*)d_in[11];
  const float* b_t1  = (const float*)d_in[12];
  const float* w_t2  = (const float*)d_in[13];
  const float* b_t2  = (const float*)d_in[14];
  float* out = (float*)d_out;

  // ---- workspace layout (~201 MB + stats) ----
  // A (67MB): pool ping / dwconv out / diff in-place
  // B (67MB): pool pong (dwconv input)
  // comb (67MB): accumulator
  // T (bf16, 100MB) overlays A+B during temporal phase
  char* ws = (char*)d_ws;
  float* A    = (float*)ws;                          // CHWX floats
  float* B    = A + (size_t)CHWX;                    // CHWX floats
  float* comb = B + (size_t)CHWX;                    // CHWX floats
  bf16*  T    = (bf16*)ws;                           // 3*CHWX bf16 (overlays A,B)
  float* stats = comb + (size_t)CHWX;
  float* s1 = stats;        // 704
  float* s2 = stats + 704;  // 704
  float* mu = stats + 1408; // 704
  float* rs = stats + 2112; // 704

  hipMemsetAsync(s1, 0, 1408 * sizeof(float), stream);

  dim3 blk(256);
  int gridE = CHWX / 256;                   // 65536 blocks
  dim3 gridP(HWX / 256, 1, CC);             // (1024,1,64)
  dim3 gridT(HWX / 256, 3, CC);             // (1024,3,64)
  float invHW = 1.f / (float)HWX;

  const float* wk[2][2] = {{w_wt5, w_bt5}, {w_wt9, w_bt9}};
  const float* bk[2][2] = {{b_wt5, b_bt5}, {b_wt9, b_bt9}};

  int first = 1;
  for (int ki = 0; ki < 2; ++ki){
    for (int br = 0; br < 2; ++br){
      // ---- morphology (separable): x->A->B->A->B ----
      if (ki == 0){
        if (br == 0){ // closing: maxpool then minpool, k=5
          pool1d<true , true , 2><<<gridE, blk, 0, stream>>>(x, A);
          pool1d<true , false, 2><<<gridE, blk, 0, stream>>>(A, B);
          pool1d<false, true , 2><<<gridE, blk, 0, stream>>>(B, A);
          pool1d<false, false, 2><<<gridE, blk, 0, stream>>>(A, B);
        } else {      // opening: minpool then maxpool, k=5
          pool1d<false, true , 2><<<gridE, blk, 0, stream>>>(x, A);
          pool1d<false, false, 2><<<gridE, blk, 0, stream>>>(A, B);
          pool1d<true , true , 2><<<gridE, blk, 0, stream>>>(B, A);
          pool1d<true , false, 2><<<gridE, blk, 0, stream>>>(A, B);
        }
      } else {
        if (br == 0){ // closing k=9
          pool1d<true , true , 4><<<gridE, blk, 0, stream>>>(x, A);
          pool1d<true , false, 4><<<gridE, blk, 0, stream>>>(A, B);
          pool1d<false, true , 4><<<gridE, blk, 0, stream>>>(B, A);
          pool1d<false, false, 4><<<gridE, blk, 0, stream>>>(A, B);
        } else {      // opening k=9
          pool1d<false, true , 4><<<gridE, blk, 0, stream>>>(x, A);
          pool1d<false, false, 4><<<gridE, blk, 0, stream>>>(A, B);
          pool1d<true , true , 4><<<gridE, blk, 0, stream>>>(B, A);
          pool1d<true , false, 4><<<gridE, blk, 0, stream>>>(A, B);
        }
      }
      int st = (ki * 2 + br) * 2;           // conv-stage stats offset (x64)
      if (ki == 0)
        dwconv_stats<5><<<gridP, blk, 0, stream>>>(B, wk[ki][br], bk[ki][br], A,
                                                   s1 + st * 64, s2 + st * 64);
      else
        dwconv_stats<9><<<gridP, blk, 0, stream>>>(B, wk[ki][br], bk[ki][br], A,
                                                   s1 + st * 64, s2 + st * 64);
      finalize_stats<<<1, 256, 0, stream>>>(s1 + st * 64, s2 + st * 64,
                                            mu + st * 64, rs + st * 64, 64, invHW);
      float sgn = (br == 0) ? -1.f : 1.f;   // WTHAM: x - wth ; BTHAM: bth - x
      diff_stats<<<gridP, blk, 0, stream>>>(A, x, mu + st * 64, rs + st * 64, sgn,
                                            s1 + (st + 1) * 64, s2 + (st + 1) * 64);
      finalize_stats<<<1, 256, 0, stream>>>(s1 + (st + 1) * 64, s2 + (st + 1) * 64,
                                            mu + (st + 1) * 64, rs + (st + 1) * 64,
                                            64, invHW);
      conv3_acc<<<gridP, blk, 0, stream>>>(A, mu + (st + 1) * 64, rs + (st + 1) * 64,
                                           w_wn, b_wn, comb, first);
      first = 0;
    }
  }

  // ---- temporal cross ----
  conv3d1<<<gridT, blk, 0, stream>>>(comb, w_t1, b_t1, T, s1 + 512, s2 + 512);
  finalize_stats<<<1, 256, 0, stream>>>(s1 + 512, s2 + 512, mu + 512, rs + 512,
                                        192, invHW);
  conv3d2_final<<<gridP, blk, 0, stream>>>(T, mu + 512, rs + 512, w_t2, b_t2, x, out);
}

// Round 3
// 4233.200 us; speedup vs baseline: 1.9397x; 1.9397x over previous
//
#include <hip/hip_runtime.h>
#include <hip/hip_bf16.h>

#define CC 64
#define HH 512
#define WWI 512
#define HWX (HH*WWI)
#define CHWX (CC*HWX)
#define EPSV 1e-5f

using bf16 = __hip_bfloat16;

__device__ __forceinline__ float b2f(bf16 v){ return __bfloat162float(v); }
__device__ __forceinline__ bf16 f2b(float v){ return __float2bfloat16(v); }

// 256-thread block. Reduce (v1,v2) across block, atomicAdd into s1,s2.
__device__ __forceinline__ void block_reduce_atomic(float v1, float v2,
                                                    float* s1, float* s2){
  #pragma unroll
  for (int o = 32; o > 0; o >>= 1){
    v1 += __shfl_down(v1, o);
    v2 += __shfl_down(v2, o);
  }
  __shared__ float a1[4], a2[4];
  int lane = threadIdx.x & 63, wid = threadIdx.x >> 6;
  if (lane == 0){ a1[wid] = v1; a2[wid] = v2; }
  __syncthreads();
  if (threadIdx.x == 0){
    atomicAdd(s1, a1[0]+a1[1]+a1[2]+a1[3]);
    atomicAdd(s2, a2[0]+a2[1]+a2[2]+a2[3]);
  }
}

// ======== fused morphology: (closing|opening) with kernel 2P+1 ========
// CLOSING: maxpool2d then minpool2d. OPENING: min then max.
// All 4 separable passes in-LDS on a 32x32 output tile.
template<int P, bool CLOS>
__global__ __launch_bounds__(256) void morph2(const float* __restrict__ in,
                                              float* __restrict__ out){
  constexpr int NI = 32 + 4*P;   // stage-0 input tile
  constexpr int NM = 32 + 2*P;   // intermediate tile
  __shared__ float b0[NI*(NI+1)];
  __shared__ float b1[NI*(NM+1)];
  const int c = blockIdx.z;
  const int x0 = blockIdx.x * 32, y0 = blockIdx.y * 32;
  const float* ip = in + (size_t)c * HWX;
  const int tid = threadIdx.x;
  // load input, clamp-to-edge (exact for pooling)
  for (int i = tid; i < NI*NI; i += 256){
    int r = i / NI, cc = i - r*NI;
    int gy = min(max(y0 - 2*P + r, 0), HH-1);
    int gx = min(max(x0 - 2*P + cc, 0), WWI-1);
    b0[r*(NI+1)+cc] = ip[gy*WWI + gx];
  }
  __syncthreads();
  // pass 1: op1 over rows (horizontal)
  for (int i = tid; i < NI*NM; i += 256){
    int r = i / NM, cc = i - r*NM;
    const float* p = &b0[r*(NI+1)+cc];
    float m = p[0];
    #pragma unroll
    for (int j = 1; j <= 2*P; ++j)
      m = CLOS ? fmaxf(m, p[j]) : fminf(m, p[j]);
    b1[r*(NM+1)+cc] = m;
  }
  __syncthreads();
  // pass 2: op1 over cols -> stage-1 pool result; mask OOB positions to
  // the op2-neutral so the second pool ignores them (reduce_window pad)
  for (int i = tid; i < NM*NM; i += 256){
    int r = i / NM, cc = i - r*NM;
    const float* p = &b1[r*(NM+1)+cc];
    float m = p[0];
    #pragma unroll
    for (int j = 1; j <= 2*P; ++j)
      m = CLOS ? fmaxf(m, p[j*(NM+1)]) : fminf(m, p[j*(NM+1)]);
    int gy = y0 - P + r, gx = x0 - P + cc;
    bool ok = ((unsigned)gy < HH) && ((unsigned)gx < WWI);
    m = ok ? m : (CLOS ? 3.4e38f : -3.4e38f);
    b0[r*(NM+1)+cc] = m;
  }
  __syncthreads();
  // pass 3: op2 over rows
  for (int i = tid; i < NM*32; i += 256){
    int r = i >> 5, cc = i & 31;
    const float* p = &b0[r*(NM+1)+cc];
    float m = p[0];
    #pragma unroll
    for (int j = 1; j <= 2*P; ++j)
      m = CLOS ? fminf(m, p[j]) : fmaxf(m, p[j]);
    b1[r*33+cc] = m;
  }
  __syncthreads();
  // pass 4: op2 over cols, store
  float* op = out + (size_t)c * HWX;
  for (int i = tid; i < 1024; i += 256){
    int r = i >> 5, cc = i & 31;
    const float* p = &b1[r*33+cc];
    float m = p[0];
    #pragma unroll
    for (int j = 1; j <= 2*P; ++j)
      m = CLOS ? fminf(m, p[j*33]) : fmaxf(m, p[j*33]);
    op[(y0+r)*WWI + x0+cc] = m;
  }
}

// ======== depthwise KxK conv (zero pad), LDS tile, 4 outputs/thread ========
template<int K>
__global__ __launch_bounds__(256) void dwconv_stats(const float* __restrict__ in,
    const float* __restrict__ wgt, const float* __restrict__ bias,
    float* __restrict__ outF, float* __restrict__ s1, float* __restrict__ s2){
  constexpr int P = K/2;
  constexpr int NT = 32 + 2*P;
  __shared__ float S[NT*(NT+1)];
  const int c = blockIdx.z;
  const int x0 = blockIdx.x*32, y0 = blockIdx.y*32;
  const float* ip = in + (size_t)c*HWX;
  const float* wp = wgt + c*K*K;      // block-uniform -> scalar loads
  const int tid = threadIdx.x;
  for (int i = tid; i < NT*NT; i += 256){
    int r = i / NT, cc = i - r*NT;
    int gy = y0 - P + r, gx = x0 - P + cc;
    bool ok = ((unsigned)gy < HH) && ((unsigned)gx < WWI);
    S[r*(NT+1)+cc] = ok ? ip[gy*WWI+gx] : 0.f;
  }
  __syncthreads();
  const int tx = tid & 31, tr0 = (tid >> 5) * 4;   // 4 output rows/thread
  float b = bias[c];
  float acc[4] = {b,b,b,b};
  #pragma unroll
  for (int dx = 0; dx < K; ++dx){
    float v[2*P+4];
    #pragma unroll
    for (int i = 0; i < 2*P+4; ++i) v[i] = S[(tr0+i)*(NT+1) + tx + dx];
    #pragma unroll
    for (int dy = 0; dy < K; ++dy){
      float w = wp[dy*K+dx];
      #pragma unroll
      for (int r = 0; r < 4; ++r) acc[r] += w * v[r+dy];
    }
  }
  float sv = 0.f, sq = 0.f;
  float* op = outF + (size_t)c*HWX;
  #pragma unroll
  for (int r = 0; r < 4; ++r){
    op[(y0+tr0+r)*WWI + x0+tx] = acc[r];
    sv += acc[r]; sq += acc[r]*acc[r];
  }
  block_reduce_atomic(sv, sq, s1+c, s2+c);
}

// -------- mu/rsqrt finalize --------
__global__ void finalize_stats(const float* __restrict__ s1,
                               const float* __restrict__ s2,
                               float* __restrict__ mu, float* __restrict__ rs,
                               int n, float invN){
  int i = blockIdx.x * 256 + threadIdx.x;
  if (i >= n) return;
  float m = s1[i] * invN;
  float v = fmaxf(s2[i] * invN - m * m, 0.f);
  mu[i] = m;
  rs[i] = rsqrtf(v + EPSV);
}

// -------- d = sgn*(relu(norm(F)) - x), in-place, + stats --------
__global__ __launch_bounds__(256) void diff_stats(float* __restrict__ F,
    const float* __restrict__ x,
    const float* __restrict__ mu, const float* __restrict__ rs,
    float sgn, float* __restrict__ s1, float* __restrict__ s2){
  int c = blockIdx.z;
  size_t i = (size_t)c * HWX + blockIdx.x * 256 + threadIdx.x;
  float t = fmaxf((F[i] - mu[c]) * rs[c], 0.f);
  float d = sgn * (t - x[i]);
  F[i] = d;
  block_reduce_atomic(d, d * d, s1 + c, s2 + c);
}

// -------- 3x3 depthwise conv of normalized d, accumulate into comb --------
// conv3(norm(d)) = rs*(conv3_nobias(d) - mu*sum_valid(w)) + b
__global__ __launch_bounds__(256) void conv3_acc(const float* __restrict__ F,
    const float* __restrict__ mu, const float* __restrict__ rs,
    const float* __restrict__ w3, const float* __restrict__ b3,
    float* __restrict__ comb, int first){
  int c = blockIdx.z;
  int pix = blockIdx.x * 256 + threadIdx.x;
  int y = pix >> 9, xw = pix & (WWI - 1);
  const float* ip = F + (size_t)c * HWX;
  const float* wp = w3 + c * 9;       // block-uniform -> scalar loads
  float acc = 0.f, wsum = 0.f;
  #pragma unroll
  for (int dy = -1; dy <= 1; ++dy){
    int yy = y + dy;
    bool yok = (unsigned)yy < HH;
    int rowb = min(max(yy, 0), HH-1) * WWI;
    #pragma unroll
    for (int dx = -1; dx <= 1; ++dx){
      int xx = xw + dx;
      bool ok = yok && ((unsigned)xx < WWI);
      float v = ip[rowb + min(max(xx, 0), WWI-1)];   // unconditional load
      float w = wp[(dy+1)*3 + dx+1];
      if (!ok) v = 0.f;
      acc += w * v;
      wsum += ok ? w : 0.f;
    }
  }
  float o = rs[c] * (acc - mu[c] * wsum) + b3[c];
  size_t oi = (size_t)c * HWX + pix;
  comb[oi] = first ? o : (comb[oi] + o);
}

// ======== Conv3d #1: all 3 output channels per thread ========
__global__ __launch_bounds__(256) void conv3d1(const float* __restrict__ comb,
    const float* __restrict__ wt, const float* __restrict__ bt,
    bf16* __restrict__ T, float* __restrict__ s1, float* __restrict__ s2){
  const int d = blockIdx.z;
  int pix = blockIdx.x * 256 + threadIdx.x;
  int y = pix >> 9, xw = pix & (WWI - 1);
  float a0 = bt[0], a1 = bt[1], a2 = bt[2];
  #pragma unroll
  for (int dd = 0; dd < 3; ++dd){
    int dz = d + dd - 1;
    bool zok = (unsigned)dz < CC;
    const float* base = comb + (size_t)min(max(dz,0),CC-1) * HWX;
    #pragma unroll
    for (int dh = 0; dh < 3; ++dh){
      int yy = y + dh - 1;
      bool yok = zok && ((unsigned)yy < HH);
      int rowb = min(max(yy,0),HH-1) * WWI;
      #pragma unroll
      for (int dw = 0; dw < 3; ++dw){
        int xx = xw + dw - 1;
        bool ok = yok && ((unsigned)xx < WWI);
        float v = base[rowb + min(max(xx,0),WWI-1)]; // unconditional load
        if (!ok) v = 0.f;
        int t = dd*9 + dh*3 + dw;
        a0 += wt[t]      * v;   // wt[] block-constant indices -> s_load
        a1 += wt[27 + t] * v;
        a2 += wt[54 + t] * v;
      }
    }
  }
  bf16 h0 = f2b(a0), h1 = f2b(a1), h2 = f2b(a2);
  float v0 = b2f(h0), v1 = b2f(h1), v2 = b2f(h2);  // stats match stored bf16
  T[(size_t)(0*CC + d)*HWX + pix] = h0;
  T[(size_t)(1*CC + d)*HWX + pix] = h1;
  T[(size_t)(2*CC + d)*HWX + pix] = h2;
  // 6-value block reduction -> 6 atomics
  float vals[6] = {v0, v0*v0, v1, v1*v1, v2, v2*v2};
  #pragma unroll
  for (int o = 32; o > 0; o >>= 1)
    #pragma unroll
    for (int k = 0; k < 6; ++k) vals[k] += __shfl_down(vals[k], o);
  __shared__ float a[4][6];
  int lane = threadIdx.x & 63, wid = threadIdx.x >> 6;
  if (lane == 0)
    #pragma unroll
    for (int k = 0; k < 6; ++k) a[wid][k] = vals[k];
  __syncthreads();
  if (threadIdx.x == 0){
    #pragma unroll
    for (int oc = 0; oc < 3; ++oc){
      atomicAdd(s1 + oc*CC + d, a[0][2*oc]  +a[1][2*oc]  +a[2][2*oc]  +a[3][2*oc]);
      atomicAdd(s2 + oc*CC + d, a[0][2*oc+1]+a[1][2*oc+1]+a[2][2*oc+1]+a[3][2*oc+1]);
    }
  }
}

// ======== Conv3d #2 on relu(norm(T)) + sigmoid-gate epilogue ========
__global__ __launch_bounds__(256) void conv3d2_final(const bf16* __restrict__ T,
    const float* __restrict__ mu, const float* __restrict__ rs,
    const float* __restrict__ wt2, const float* __restrict__ bt2,
    const float* __restrict__ x, float* __restrict__ out){
  const int d = blockIdx.z;
  int pix = blockIdx.x * 256 + threadIdx.x;
  int y = pix >> 9, xw = pix & (WWI - 1);
  float acc = bt2[0];
  #pragma unroll
  for (int i3 = 0; i3 < 3; ++i3){
    #pragma unroll
    for (int dd = 0; dd < 3; ++dd){
      int dz = d + dd - 1;
      bool zok = (unsigned)dz < CC;
      int ch = i3*CC + min(max(dz,0),CC-1);   // block-uniform
      float r  = rs[ch];
      float mr = mu[ch] * r;
      const bf16* tp = T + (size_t)ch * HWX;
      #pragma unroll
      for (int dh = 0; dh < 3; ++dh){
        int yy = y + dh - 1;
        bool yok = zok && ((unsigned)yy < HH);
        int rowb = min(max(yy,0),HH-1) * WWI;
        #pragma unroll
        for (int dw = 0; dw < 3; ++dw){
          int xx = xw + dw - 1;
          bool ok = yok && ((unsigned)xx < WWI);
          float tv = b2f(tp[rowb + min(max(xx,0),WWI-1)]);  // unconditional
          float u = fmaxf(fmaf(tv, r, -mr), 0.f);
          if (!ok) u = 0.f;
          acc += wt2[(i3*3+dd)*9 + dh*3 + dw] * u;
        }
      }
    }
  }
  float sg = 1.f / (1.f + __expf(-acc));
  size_t gi = (size_t)d * HWX + pix;
  out[gi] = fmaxf(x[gi] * sg, 0.f);
}

extern "C" void kernel_launch(void* const* d_in, const int* in_sizes, int n_in,
                              void* d_out, int out_size, void* d_ws, size_t ws_size,
                              hipStream_t stream){
  const float* x     = (const float*)d_in[0];
  const float* w_wt5 = (const float*)d_in[1];
  const float* b_wt5 = (const float*)d_in[2];
  const float* w_wt9 = (const float*)d_in[3];
  const float* b_wt9 = (const float*)d_in[4];
  const float* w_bt5 = (const float*)d_in[5];
  const float* b_bt5 = (const float*)d_in[6];
  const float* w_bt9 = (const float*)d_in[7];
  const float* b_bt9 = (const float*)d_in[8];
  const float* w_wn  = (const float*)d_in[9];
  const float* b_wn  = (const float*)d_in[10];
  const float* w_t1  = (const float*)d_in[11];
  const float* b_t1  = (const float*)d_in[12];
  const float* w_t2  = (const float*)d_in[13];
  const float* b_t2  = (const float*)d_in[14];
  float* out = (float*)d_out;

  // ---- workspace layout ----
  // A: dwconv out / diff in-place; B: morph out; comb: accumulator
  // T (bf16, 3*CHWX) overlays A+B during temporal phase
  char* ws = (char*)d_ws;
  float* A    = (float*)ws;
  float* B    = A + (size_t)CHWX;
  float* comb = B + (size_t)CHWX;
  bf16*  T    = (bf16*)ws;
  float* stats = comb + (size_t)CHWX;
  float* s1 = stats;
  float* s2 = stats + 704;
  float* mu = stats + 1408;
  float* rs = stats + 2112;

  hipMemsetAsync(s1, 0, 1408 * sizeof(float), stream);

  dim3 blk(256);
  dim3 gridM(WWI/32, HH/32, CC);            // (16,16,64)
  dim3 gridP(HWX / 256, 1, CC);             // (1024,1,64)
  float invHW = 1.f / (float)HWX;

  const float* wk[2][2] = {{w_wt5, w_bt5}, {w_wt9, w_bt9}};
  const float* bk[2][2] = {{b_wt5, b_bt5}, {b_wt9, b_bt9}};

  int first = 1;
  for (int ki = 0; ki < 2; ++ki){
    for (int br = 0; br < 2; ++br){
      // ---- fused morphology -> B ----
      if (ki == 0){
        if (br == 0) morph2<2, true ><<<gridM, blk, 0, stream>>>(x, B);
        else         morph2<2, false><<<gridM, blk, 0, stream>>>(x, B);
      } else {
        if (br == 0) morph2<4, true ><<<gridM, blk, 0, stream>>>(x, B);
        else         morph2<4, false><<<gridM, blk, 0, stream>>>(x, B);
      }
      int st = (ki * 2 + br) * 2;
      if (ki == 0)
        dwconv_stats<5><<<gridM, blk, 0, stream>>>(B, wk[ki][br], bk[ki][br], A,
                                                   s1 + st * 64, s2 + st * 64);
      else
        dwconv_stats<9><<<gridM, blk, 0, stream>>>(B, wk[ki][br], bk[ki][br], A,
                                                   s1 + st * 64, s2 + st * 64);
      finalize_stats<<<1, 256, 0, stream>>>(s1 + st * 64, s2 + st * 64,
                                            mu + st * 64, rs + st * 64, 64, invHW);
      float sgn = (br == 0) ? -1.f : 1.f;   // WTHAM: x - wth ; BTHAM: bth - x
      diff_stats<<<gridP, blk, 0, stream>>>(A, x, mu + st * 64, rs + st * 64, sgn,
                                            s1 + (st + 1) * 64, s2 + (st + 1) * 64);
      finalize_stats<<<1, 256, 0, stream>>>(s1 + (st + 1) * 64, s2 + (st + 1) * 64,
                                            mu + (st + 1) * 64, rs + (st + 1) * 64,
                                            64, invHW);
      conv3_acc<<<gridP, blk, 0, stream>>>(A, mu + (st + 1) * 64, rs + (st + 1) * 64,
                                           w_wn, b_wn, comb, first);
      first = 0;
    }
  }

  // ---- temporal cross ----
  conv3d1<<<gridP, blk, 0, stream>>>(comb, w_t1, b_t1, T, s1 + 512, s2 + 512);
  finalize_stats<<<1, 256, 0, stream>>>(s1 + 512, s2 + 512, mu + 512, rs + 512,
                                        192, invHW);
  conv3d2_final<<<gridP, blk, 0, stream>>>(T, mu + 512, rs + 512, w_t2, b_t2, x, out);
}

// Round 4
// 2326.375 us; speedup vs baseline: 3.5297x; 1.8197x over previous
//
#include <hip/hip_runtime.h>
#include <hip/hip_bf16.h>

#define CC 64
#define HH 512
#define WWI 512
#define HWX (HH*WWI)
#define CHWX (CC*HWX)
#define EPSV 1e-5f

using bf16 = __hip_bfloat16;

__device__ __forceinline__ float b2f(bf16 v){ return __bfloat162float(v); }
__device__ __forceinline__ bf16 f2b(float v){ return __float2bfloat16(v); }

// norm params from raw sums (block-uniform scalar math)
__device__ __forceinline__ void mk_norm(const float* s1, const float* s2, int c,
                                        float invN, float& m, float& r){
  m = s1[c] * invN;
  float v = fmaxf(s2[c] * invN - m * m, 0.f);
  r = rsqrtf(v + EPSV);
}

// 256-thread block. Reduce (v1,v2) across block, atomicAdd into s1,s2.
__device__ __forceinline__ void block_reduce_atomic(float v1, float v2,
                                                    float* s1, float* s2){
  #pragma unroll
  for (int o = 32; o > 0; o >>= 1){
    v1 += __shfl_down(v1, o);
    v2 += __shfl_down(v2, o);
  }
  __shared__ float a1[4], a2[4];
  int lane = threadIdx.x & 63, wid = threadIdx.x >> 6;
  if (lane == 0){ a1[wid] = v1; a2[wid] = v2; }
  __syncthreads();
  if (threadIdx.x == 0){
    atomicAdd(s1, a1[0]+a1[1]+a1[2]+a1[3]);
    atomicAdd(s2, a2[0]+a2[1]+a2[2]+a2[3]);
  }
}

// ======== fused morphology: (closing|opening) with kernel 2P+1 ========
template<int P, bool CLOS>
__global__ __launch_bounds__(256) void morph2(const float* __restrict__ in,
                                              float* __restrict__ out){
  constexpr int NI = 32 + 4*P;   // stage-0 input tile
  constexpr int NM = 32 + 2*P;   // intermediate tile
  __shared__ float b0[NI*(NI+1)];
  __shared__ float b1[NI*(NM+1)];
  const int c = blockIdx.z;
  const int x0 = blockIdx.x * 32, y0 = blockIdx.y * 32;
  const float* ip = in + (size_t)c * HWX;
  const int tid = threadIdx.x;
  for (int i = tid; i < NI*NI; i += 256){
    int r = i / NI, cc = i - r*NI;
    int gy = min(max(y0 - 2*P + r, 0), HH-1);
    int gx = min(max(x0 - 2*P + cc, 0), WWI-1);
    b0[r*(NI+1)+cc] = ip[gy*WWI + gx];
  }
  __syncthreads();
  for (int i = tid; i < NI*NM; i += 256){
    int r = i / NM, cc = i - r*NM;
    const float* p = &b0[r*(NI+1)+cc];
    float m = p[0];
    #pragma unroll
    for (int j = 1; j <= 2*P; ++j)
      m = CLOS ? fmaxf(m, p[j]) : fminf(m, p[j]);
    b1[r*(NM+1)+cc] = m;
  }
  __syncthreads();
  for (int i = tid; i < NM*NM; i += 256){
    int r = i / NM, cc = i - r*NM;
    const float* p = &b1[r*(NM+1)+cc];
    float m = p[0];
    #pragma unroll
    for (int j = 1; j <= 2*P; ++j)
      m = CLOS ? fmaxf(m, p[j*(NM+1)]) : fminf(m, p[j*(NM+1)]);
    int gy = y0 - P + r, gx = x0 - P + cc;
    bool ok = ((unsigned)gy < HH) && ((unsigned)gx < WWI);
    m = ok ? m : (CLOS ? 3.4e38f : -3.4e38f);
    b0[r*(NM+1)+cc] = m;
  }
  __syncthreads();
  for (int i = tid; i < NM*32; i += 256){
    int r = i >> 5, cc = i & 31;
    const float* p = &b0[r*(NM+1)+cc];
    float m = p[0];
    #pragma unroll
    for (int j = 1; j <= 2*P; ++j)
      m = CLOS ? fminf(m, p[j]) : fmaxf(m, p[j]);
    b1[r*33+cc] = m;
  }
  __syncthreads();
  float* op = out + (size_t)c * HWX;
  for (int i = tid; i < 1024; i += 256){
    int r = i >> 5, cc = i & 31;
    const float* p = &b1[r*33+cc];
    float m = p[0];
    #pragma unroll
    for (int j = 1; j <= 2*P; ++j)
      m = CLOS ? fminf(m, p[j*33]) : fmaxf(m, p[j*33]);
    op[(y0+r)*WWI + x0+cc] = m;
  }
}

// ======== depthwise KxK conv (zero pad), LDS tile, 4 outputs/thread ========
template<int K>
__global__ __launch_bounds__(256) void dwconv_stats(const float* __restrict__ in,
    const float* __restrict__ wgt, const float* __restrict__ bias,
    float* __restrict__ outF, float* __restrict__ s1, float* __restrict__ s2){
  constexpr int P = K/2;
  constexpr int NT = 32 + 2*P;
  __shared__ float S[NT*(NT+1)];
  const int c = blockIdx.z;
  const int x0 = blockIdx.x*32, y0 = blockIdx.y*32;
  const float* ip = in + (size_t)c*HWX;
  const float* wp = wgt + c*K*K;
  const int tid = threadIdx.x;
  for (int i = tid; i < NT*NT; i += 256){
    int r = i / NT, cc = i - r*NT;
    int gy = y0 - P + r, gx = x0 - P + cc;
    bool ok = ((unsigned)gy < HH) && ((unsigned)gx < WWI);
    float v = ip[min(max(gy,0),HH-1)*WWI + min(max(gx,0),WWI-1)];
    S[r*(NT+1)+cc] = ok ? v : 0.f;
  }
  __syncthreads();
  const int tx = tid & 31, tr0 = (tid >> 5) * 4;
  float b = bias[c];
  float acc[4] = {b,b,b,b};
  #pragma unroll
  for (int dx = 0; dx < K; ++dx){
    float v[2*P+4];
    #pragma unroll
    for (int i = 0; i < 2*P+4; ++i) v[i] = S[(tr0+i)*(NT+1) + tx + dx];
    #pragma unroll
    for (int dy = 0; dy < K; ++dy){
      float w = wp[dy*K+dx];
      #pragma unroll
      for (int r = 0; r < 4; ++r) acc[r] += w * v[r+dy];
    }
  }
  float sv = 0.f, sq = 0.f;
  float* op = outF + (size_t)c*HWX;
  #pragma unroll
  for (int r = 0; r < 4; ++r){
    op[(y0+tr0+r)*WWI + x0+tx] = acc[r];
    sv += acc[r]; sq += acc[r]*acc[r];
  }
  block_reduce_atomic(sv, sq, s1+c, s2+c);
}

// -------- d = sgn*(relu(norm(F)) - x), float4, in-place, + stats --------
__global__ __launch_bounds__(256) void diff_stats4(float4* __restrict__ F,
    const float4* __restrict__ x,
    const float* __restrict__ s1i, const float* __restrict__ s2i, float invN,
    float sgn, float* __restrict__ s1, float* __restrict__ s2){
  int c = blockIdx.z;
  float m, r;
  mk_norm(s1i, s2i, c, invN, m, r);
  size_t i = (size_t)c * (HWX/4) + blockIdx.x * 256 + threadIdx.x;
  float4 f = F[i], xv = x[i];
  float d0 = sgn * (fmaxf((f.x - m) * r, 0.f) - xv.x);
  float d1 = sgn * (fmaxf((f.y - m) * r, 0.f) - xv.y);
  float d2 = sgn * (fmaxf((f.z - m) * r, 0.f) - xv.z);
  float d3 = sgn * (fmaxf((f.w - m) * r, 0.f) - xv.w);
  F[i] = make_float4(d0, d1, d2, d3);
  block_reduce_atomic(d0+d1+d2+d3, d0*d0+d1*d1+d2*d2+d3*d3, s1 + c, s2 + c);
}

// ======== 3x3 dwconv of norm(d): normalize at LDS stage, zero-pad ========
__global__ __launch_bounds__(256) void conv3_acc(const float* __restrict__ F,
    const float* __restrict__ s1i, const float* __restrict__ s2i, float invN,
    const float* __restrict__ w3, const float* __restrict__ b3,
    float* __restrict__ comb, int first){
  __shared__ float S[34*35];
  const int c = blockIdx.z;
  const int x0 = blockIdx.x*32, y0 = blockIdx.y*32;
  float m, r;
  mk_norm(s1i, s2i, c, invN, m, r);
  const float* ip = F + (size_t)c*HWX;
  const float* wp = w3 + c*9;
  for (int i = threadIdx.x; i < 34*34; i += 256){
    int rr = i / 34, cc = i - rr*34;
    int gy = y0 - 1 + rr, gx = x0 - 1 + cc;
    bool ok = ((unsigned)gy < HH) && ((unsigned)gx < WWI);
    float v = ip[min(max(gy,0),HH-1)*WWI + min(max(gx,0),WWI-1)];
    S[rr*35+cc] = ok ? (v - m) * r : 0.f;
  }
  __syncthreads();
  const int tx = threadIdx.x & 31, tr0 = (threadIdx.x >> 5) * 4;
  float b = b3[c];
  float acc[4] = {b,b,b,b};
  #pragma unroll
  for (int dx = 0; dx < 3; ++dx){
    float v[6];
    #pragma unroll
    for (int i = 0; i < 6; ++i) v[i] = S[(tr0+i)*35 + tx + dx];
    #pragma unroll
    for (int dy = 0; dy < 3; ++dy){
      float w = wp[dy*3+dx];
      #pragma unroll
      for (int rr = 0; rr < 4; ++rr) acc[rr] += w * v[rr+dy];
    }
  }
  float* op = comb + (size_t)c*HWX;
  #pragma unroll
  for (int rr = 0; rr < 4; ++rr){
    size_t oi = (size_t)(y0+tr0+rr)*WWI + x0+tx;
    op[oi] = first ? acc[rr] : (op[oi] + acc[rr]);
  }
}

// ======== Conv3d #1: LDS-staged 3 planes, 3 ocs x 4 rows per thread ========
__global__ __launch_bounds__(256) void conv3d1(const float* __restrict__ comb,
    const float* __restrict__ wt, const float* __restrict__ bt,
    bf16* __restrict__ T, float* __restrict__ s1, float* __restrict__ s2){
  __shared__ float S[3][34*35];
  const int d = blockIdx.z;
  const int x0 = blockIdx.x*32, y0 = blockIdx.y*32;
  #pragma unroll
  for (int dd = 0; dd < 3; ++dd){
    int dz = d + dd - 1;
    bool zok = (unsigned)dz < CC;
    const float* ip = comb + (size_t)min(max(dz,0),CC-1) * HWX;
    for (int i = threadIdx.x; i < 34*34; i += 256){
      int rr = i / 34, cc = i - rr*34;
      int gy = y0 - 1 + rr, gx = x0 - 1 + cc;
      bool ok = zok && ((unsigned)gy < HH) && ((unsigned)gx < WWI);
      float v = ip[min(max(gy,0),HH-1)*WWI + min(max(gx,0),WWI-1)];
      S[dd][rr*35+cc] = ok ? v : 0.f;
    }
  }
  __syncthreads();
  const int tx = threadIdx.x & 31, tr0 = (threadIdx.x >> 5) * 4;
  float acc[3][4];
  #pragma unroll
  for (int oc = 0; oc < 3; ++oc){
    float b = bt[oc];
    #pragma unroll
    for (int rr = 0; rr < 4; ++rr) acc[oc][rr] = b;
  }
  #pragma unroll
  for (int dd = 0; dd < 3; ++dd){
    #pragma unroll
    for (int dx = 0; dx < 3; ++dx){
      float v[6];
      #pragma unroll
      for (int i = 0; i < 6; ++i) v[i] = S[dd][(tr0+i)*35 + tx + dx];
      #pragma unroll
      for (int dy = 0; dy < 3; ++dy){
        #pragma unroll
        for (int oc = 0; oc < 3; ++oc){
          float w = wt[oc*27 + dd*9 + dy*3 + dx];
          #pragma unroll
          for (int rr = 0; rr < 4; ++rr) acc[oc][rr] += w * v[rr+dy];
        }
      }
    }
  }
  float vals[6] = {0,0,0,0,0,0};
  #pragma unroll
  for (int oc = 0; oc < 3; ++oc){
    bf16* tp = T + (size_t)(oc*CC + d)*HWX;
    #pragma unroll
    for (int rr = 0; rr < 4; ++rr){
      bf16 h = f2b(acc[oc][rr]);
      tp[(size_t)(y0+tr0+rr)*WWI + x0+tx] = h;
      float av = b2f(h);                 // stats match stored bf16
      vals[2*oc]   += av;
      vals[2*oc+1] += av*av;
    }
  }
  #pragma unroll
  for (int o = 32; o > 0; o >>= 1)
    #pragma unroll
    for (int k = 0; k < 6; ++k) vals[k] += __shfl_down(vals[k], o);
  __shared__ float red[4][6];
  int lane = threadIdx.x & 63, wid = threadIdx.x >> 6;
  if (lane == 0)
    #pragma unroll
    for (int k = 0; k < 6; ++k) red[wid][k] = vals[k];
  __syncthreads();
  if (threadIdx.x == 0){
    #pragma unroll
    for (int oc = 0; oc < 3; ++oc){
      atomicAdd(s1 + oc*CC + d, red[0][2*oc]  +red[1][2*oc]  +red[2][2*oc]  +red[3][2*oc]);
      atomicAdd(s2 + oc*CC + d, red[0][2*oc+1]+red[1][2*oc+1]+red[2][2*oc+1]+red[3][2*oc+1]);
    }
  }
}

// ======== Conv3d #2: stage 9 relu-normalized planes in LDS, then conv ========
__global__ __launch_bounds__(256) void conv3d2_final(const bf16* __restrict__ T,
    const float* __restrict__ s1i, const float* __restrict__ s2i, float invN,
    const float* __restrict__ wt2, const float* __restrict__ bt2,
    const float* __restrict__ x, float* __restrict__ out){
  __shared__ float S[9][34*35];
  const int d = blockIdx.z;
  const int x0 = blockIdx.x*32, y0 = blockIdx.y*32;
  #pragma unroll
  for (int i3 = 0; i3 < 3; ++i3){
    #pragma unroll
    for (int dd = 0; dd < 3; ++dd){
      int dz = d + dd - 1;
      bool zok = (unsigned)dz < CC;
      int ch = i3*CC + min(max(dz,0),CC-1);
      float m, r;
      mk_norm(s1i, s2i, ch, invN, m, r);
      const bf16* tp = T + (size_t)ch * HWX;
      float* sp = S[i3*3+dd];
      for (int i = threadIdx.x; i < 34*34; i += 256){
        int rr = i / 34, cc = i - rr*34;
        int gy = y0 - 1 + rr, gx = x0 - 1 + cc;
        bool ok = zok && ((unsigned)gy < HH) && ((unsigned)gx < WWI);
        float tv = b2f(tp[min(max(gy,0),HH-1)*WWI + min(max(gx,0),WWI-1)]);
        sp[rr*35+cc] = ok ? fmaxf((tv - m) * r, 0.f) : 0.f;
      }
    }
  }
  __syncthreads();
  const int tx = threadIdx.x & 31, tr0 = (threadIdx.x >> 5) * 4;
  float b = bt2[0];
  float acc[4] = {b,b,b,b};
  #pragma unroll
  for (int ch = 0; ch < 9; ++ch){
    #pragma unroll
    for (int dx = 0; dx < 3; ++dx){
      float v[6];
      #pragma unroll
      for (int i = 0; i < 6; ++i) v[i] = S[ch][(tr0+i)*35 + tx + dx];
      #pragma unroll
      for (int dy = 0; dy < 3; ++dy){
        float w = wt2[ch*9 + dy*3 + dx];
        #pragma unroll
        for (int rr = 0; rr < 4; ++rr) acc[rr] += w * v[rr+dy];
      }
    }
  }
  #pragma unroll
  for (int rr = 0; rr < 4; ++rr){
    float sg = 1.f / (1.f + __expf(-acc[rr]));
    size_t gi = (size_t)d*HWX + (size_t)(y0+tr0+rr)*WWI + x0+tx;
    out[gi] = fmaxf(x[gi] * sg, 0.f);
  }
}

extern "C" void kernel_launch(void* const* d_in, const int* in_sizes, int n_in,
                              void* d_out, int out_size, void* d_ws, size_t ws_size,
                              hipStream_t stream){
  const float* x     = (const float*)d_in[0];
  const float* w_wt5 = (const float*)d_in[1];
  const float* b_wt5 = (const float*)d_in[2];
  const float* w_wt9 = (const float*)d_in[3];
  const float* b_wt9 = (const float*)d_in[4];
  const float* w_bt5 = (const float*)d_in[5];
  const float* b_bt5 = (const float*)d_in[6];
  const float* w_bt9 = (const float*)d_in[7];
  const float* b_bt9 = (const float*)d_in[8];
  const float* w_wn  = (const float*)d_in[9];
  const float* b_wn  = (const float*)d_in[10];
  const float* w_t1  = (const float*)d_in[11];
  const float* b_t1  = (const float*)d_in[12];
  const float* w_t2  = (const float*)d_in[13];
  const float* b_t2  = (const float*)d_in[14];
  float* out = (float*)d_out;

  // ---- workspace layout ----
  char* ws = (char*)d_ws;
  float* A    = (float*)ws;                  // dwconv out / diff in-place
  float* B    = A + (size_t)CHWX;            // morph out
  float* comb = B + (size_t)CHWX;            // accumulator
  bf16*  T    = (bf16*)ws;                   // 3*CHWX bf16, overlays A+B
  float* stats = comb + (size_t)CHWX;
  float* s1 = stats;        // 704
  float* s2 = stats + 704;  // 704

  hipMemsetAsync(s1, 0, 1408 * sizeof(float), stream);

  dim3 blk(256);
  dim3 gridM(WWI/32, HH/32, CC);            // (16,16,64)
  dim3 gridV(HWX/4/256, 1, CC);             // (256,1,64) float4 streaming
  float invHW = 1.f / (float)HWX;

  const float* wk[2][2] = {{w_wt5, w_bt5}, {w_wt9, w_bt9}};
  const float* bk[2][2] = {{b_wt5, b_bt5}, {b_wt9, b_bt9}};

  int first = 1;
  for (int ki = 0; ki < 2; ++ki){
    for (int br = 0; br < 2; ++br){
      if (ki == 0){
        if (br == 0) morph2<2, true ><<<gridM, blk, 0, stream>>>(x, B);
        else         morph2<2, false><<<gridM, blk, 0, stream>>>(x, B);
      } else {
        if (br == 0) morph2<4, true ><<<gridM, blk, 0, stream>>>(x, B);
        else         morph2<4, false><<<gridM, blk, 0, stream>>>(x, B);
      }
      int st = (ki * 2 + br) * 2;
      if (ki == 0)
        dwconv_stats<5><<<gridM, blk, 0, stream>>>(B, wk[ki][br], bk[ki][br], A,
                                                   s1 + st*64, s2 + st*64);
      else
        dwconv_stats<9><<<gridM, blk, 0, stream>>>(B, wk[ki][br], bk[ki][br], A,
                                                   s1 + st*64, s2 + st*64);
      float sgn = (br == 0) ? -1.f : 1.f;   // WTHAM: x - wth ; BTHAM: bth - x
      diff_stats4<<<gridV, blk, 0, stream>>>((float4*)A, (const float4*)x,
                                             s1 + st*64, s2 + st*64, invHW, sgn,
                                             s1 + (st+1)*64, s2 + (st+1)*64);
      conv3_acc<<<gridM, blk, 0, stream>>>(A, s1 + (st+1)*64, s2 + (st+1)*64, invHW,
                                           w_wn, b_wn, comb, first);
      first = 0;
    }
  }

  // ---- temporal cross ----
  conv3d1<<<gridM, blk, 0, stream>>>(comb, w_t1, b_t1, T, s1 + 512, s2 + 512);
  conv3d2_final<<<gridM, blk, 0, stream>>>(T, s1 + 512, s2 + 512, invHW,
                                           w_t2, b_t2, x, out);
}